// Round 4
// baseline (461.560 us; speedup 1.0000x reference)
//
#include <hip/hip_runtime.h>

// Problem constants (T=64, B=32, I=128, H=256, alpha=0.2)
#define TT 64
#define BB 32
#define II 128
#define HH 256
#define MM (TT*BB)   // 2048

typedef __bf16  bf16x8  __attribute__((ext_vector_type(8)));
typedef float   f32x16  __attribute__((ext_vector_type(16)));
typedef _Float16 half2v __attribute__((ext_vector_type(2)));

__device__ __forceinline__ float bf2f(unsigned short u) {
    union { unsigned int i; float f; } v; v.i = ((unsigned int)u) << 16; return v.f;
}
__device__ __forceinline__ unsigned short f2bf(float f) {
    union { float f; unsigned int i; } v; v.f = f;
    unsigned int r = v.i + 0x7fffu + ((v.i >> 16) & 1u);
    return (unsigned short)(r >> 16);
}

// Dual-dtype loaders: external tensors may be fp32 or bf16; runtime flag decides.
struct F8 { float v[8]; };
__device__ __forceinline__ F8 load8(const void* base, int idx, int isf32) {
    F8 r;
    if (isf32) {
        const float4* p = (const float4*)((const float*)base + idx);
        float4 a = p[0], b = p[1];
        r.v[0]=a.x; r.v[1]=a.y; r.v[2]=a.z; r.v[3]=a.w;
        r.v[4]=b.x; r.v[5]=b.y; r.v[6]=b.z; r.v[7]=b.w;
    } else {
        uint4 u = *(const uint4*)((const unsigned short*)base + idx);
        const unsigned short* p = (const unsigned short*)&u;
#pragma unroll
        for (int j = 0; j < 8; ++j) r.v[j] = bf2f(p[j]);
    }
    return r;
}
__device__ __forceinline__ float load1(const void* base, int idx, int isf32) {
    return isf32 ? ((const float*)base)[idx]
                 : bf2f(((const unsigned short*)base)[idx]);
}

__device__ __forceinline__ float fdot2f(half2v a, half2v b, float c) {
#if __has_builtin(__builtin_amdgcn_fdot2)
    return __builtin_amdgcn_fdot2(a, b, c, false);
#else
    return c + (float)a.x*(float)b.x + (float)a.y*(float)b.y;
#endif
}

// ---------------------------------------------------------------------------
// K0: dtype sniffer (fp32 read as ushorts -> ~25% have exponent >= 0xC0).
// ---------------------------------------------------------------------------
__global__ __launch_bounds__(256) void k0_sniff(
    const unsigned short* __restrict__ x, int* __restrict__ flag)
{
    __shared__ int cnt;
    if (threadIdx.x == 0) cnt = 0;
    __syncthreads();
    int c = 0;
    for (int i = threadIdx.x; i < 8192; i += 256) {
        unsigned int e = (x[i] >> 7) & 0xFFu;
        if (e >= 0xC0u) ++c;
    }
    atomicAdd(&cnt, c);
    __syncthreads();
    if (threadIdx.x == 0) flag[0] = (cnt > 16) ? 1 : 0;
}

// ---------------------------------------------------------------------------
// K1 (unchanged): emits ipT[j][m] via LDS transpose.
// ---------------------------------------------------------------------------
__global__ __launch_bounds__(256) void k1_proj(
    const void* __restrict__ x,
    const void* __restrict__ w_i2h,
    const void* __restrict__ b_i2h,
    const void* __restrict__ w_i2c,
    const void* __restrict__ b_i2c,
    const int* __restrict__ flagp,
    unsigned short* __restrict__ ipT,
    float* __restrict__ cin)
{
    const int isf32 = *flagp;
    const int tid = threadIdx.x;
    const int h = tid;
    const int mbase = blockIdx.x * 32;
    __shared__ __align__(16) _Float16 xs[32][II];          // 8 KB
    __shared__ __align__(16) unsigned short ips[32][HH];   // 16 KB

    half2v w1[II/2], w2[II/2];
#pragma unroll
    for (int c8 = 0; c8 < II/8; ++c8) {
        F8 f1 = load8(w_i2h, h*II + c8*8, isf32);
        F8 f2 = load8(w_i2c, h*II + c8*8, isf32);
#pragma unroll
        for (int j = 0; j < 4; ++j) {
            half2v a; a.x = (_Float16)f1.v[2*j]; a.y = (_Float16)f1.v[2*j+1];
            half2v b; b.x = (_Float16)f2.v[2*j]; b.y = (_Float16)f2.v[2*j+1];
            w1[c8*4 + j] = a;
            w2[c8*4 + j] = b;
        }
    }
    const float bb1 = load1(b_i2h, h, isf32);
    const float bb2 = load1(b_i2c, h, isf32);

    for (int u = tid; u < 32*II; u += 256)
        xs[u >> 7][u & (II-1)] = (_Float16)load1(x, (mbase + (u >> 7))*II + (u & (II-1)), isf32);
    __syncthreads();

    for (int mm = 0; mm < 32; ++mm) {
        const half2v* xv = (const half2v*)xs[mm];
        float a0=0,a1=0,a2=0,a3=0, c0=0,c1=0,c2=0,c3=0;
#pragma unroll
        for (int r = 0; r < II/2; r += 4) {
            half2v x0 = xv[r], x1 = xv[r+1], x2 = xv[r+2], x3 = xv[r+3];
            a0 = fdot2f(w1[r],   x0, a0);
            a1 = fdot2f(w1[r+1], x1, a1);
            a2 = fdot2f(w1[r+2], x2, a2);
            a3 = fdot2f(w1[r+3], x3, a3);
            c0 = fdot2f(w2[r],   x0, c0);
            c1 = fdot2f(w2[r+1], x1, c1);
            c2 = fdot2f(w2[r+2], x2, c2);
            c3 = fdot2f(w2[r+3], x3, c3);
        }
        ips[mm][h] = f2bf(((a0+a1)+(a2+a3)) + bb1);
        cin[(mbase+mm)*HH + h] = ((c0+c1)+(c2+c3)) + bb2;
    }
    __syncthreads();
    unsigned short tmp[32];
#pragma unroll
    for (int mm = 0; mm < 32; ++mm) tmp[mm] = ips[mm][tid];
    uint4* dst = (uint4*)(ipT + (size_t)tid*MM + mbase);
    const uint4* s4 = (const uint4*)tmp;
    dst[0] = s4[0]; dst[1] = s4[1]; dst[2] = s4[2]; dst[3] = s4[3];
}

// ---------------------------------------------------------------------------
// K2 (unchanged): per-sample context chains, double-buffered LDS.
// ---------------------------------------------------------------------------
__global__ __launch_bounds__(256) void k2_ctx(
    const void* __restrict__ w_c2c,
    const void* __restrict__ b_c2c,
    const float* __restrict__ cin,
    const int* __restrict__ ns_ptr,
    const int* __restrict__ flagp,
    unsigned short* __restrict__ ctx_hist,
    void* __restrict__ out_base)
{
    const int isf32 = *flagp;
    const int b = blockIdx.x;
    const int h = threadIdx.x;
    const int ns = max(1, *ns_ptr);

    __shared__ __align__(16) _Float16 cs[2][HH];

    half2v w[HH/2];
#pragma unroll
    for (int c8 = 0; c8 < HH/8; ++c8) {
        F8 f = load8(w_c2c, h*HH + c8*8, isf32);
#pragma unroll
        for (int j = 0; j < 4; ++j) {
            half2v hv;
            hv.x = (_Float16)f.v[2*j];
            hv.y = (_Float16)f.v[2*j+1];
            w[c8*4 + j] = hv;
        }
    }
    const float bcc = load1(b_c2c, h, isf32);
    float ctxv = 0.0f;
    cs[0][h] = (_Float16)0.0f;
    __syncthreads();
    int cur = 0;

    for (int t = 0; t < TT; ++t) {
        const float cinv = cin[(t*BB + b)*HH + h];
        for (int s = 0; s < ns; ++s) {
            if (s == ns-1) ctx_hist[(t*BB + b)*HH + h] = f2bf(ctxv);
            float p0=0,p1=0,p2=0,p3=0;
            const float4* cp4 = (const float4*)cs[cur];
#pragma unroll
            for (int r4 = 0; r4 < HH/8; ++r4) {
                float4 blob = cp4[r4];
                const half2v* c2 = (const half2v*)&blob;
                p0 = fdot2f(w[r4*4+0], c2[0], p0);
                p1 = fdot2f(w[r4*4+1], c2[1], p1);
                p2 = fdot2f(w[r4*4+2], c2[2], p2);
                p3 = fdot2f(w[r4*4+3], c2[3], p3);
            }
            float cnew = fmaxf(((p0+p1)+(p2+p3)) + bcc + cinv, 0.0f);
            ctxv = 0.8f*ctxv + 0.2f*cnew;
            cs[cur^1][h] = (_Float16)ctxv;
            cur ^= 1;
            __syncthreads();
        }
    }
    const int cofs = MM*HH + BB*HH + b*HH + h;
    if (isf32) ((float*)out_base)[cofs] = ctxv;
    else       ((unsigned short*)out_base)[cofs] = f2bf(ctxv);
}

// ---------------------------------------------------------------------------
// K3 v7: v6 structure (16 waves, Ws resident, BK=32 dbuf, 1 barrier/chunk)
// with a register-lean epilogue that fits the 128-reg/wave envelope that a
// 1024-thread block mandates (16 waves @ 4/SIMD). v6's epilogue (bcv[32] +
// per-n pointers + transient acc reads) spilled to scratch: FETCH 286 MB /
// WRITE 107 MB of pure spill traffic. Here the bc-add and ip-multiply are
// fused into one pass with only sv[2] + b4[4] + one row pointer live.
// ---------------------------------------------------------------------------
__global__ __launch_bounds__(1024, 4) void k3_main(
    const unsigned short* __restrict__ ctx_hist,  // [2048 m,256 k] bf16 (internal)
    const void* __restrict__ wc,                  // [65536,256] external
    const void* __restrict__ bc,                  // [65536]     external
    const unsigned short* __restrict__ ipT,       // [256 j][2048 m] bf16 (internal)
    const int* __restrict__ flagp,
    float* __restrict__ outT)                     // [256 i][2048 m] f32 (internal)
{
    extern __shared__ __align__(16) unsigned char lds[];
    unsigned short* Ws  = (unsigned short*)lds;              // 131072 B
    unsigned short* As0 = (unsigned short*)(lds + 131072);   // 16384 B
    unsigned short* As1 = (unsigned short*)(lds + 147456);   // 16384 B
    float*          Ps  = (float*)(lds + 131072);            // 4 KB overlay on As0

    const int isf32 = *flagp;
    const int tid  = threadIdx.x;
    const int lane = tid & 63;
    const int wave = tid >> 6;        // 0..15
    const int i    = blockIdx.x;      // 0..255
    const int jq   = wave & 3;        // j quarter (64 rows)
    const int ms   = wave >> 2;       // m quarter (64 cols)
    const int l31  = lane & 31;
    const int lhi  = lane >> 5;

    // ---- stage Ws once: 256 j-rows x 256 k -> bf16, swizzled; 8 units/thread
#pragma unroll
    for (int p = 0; p < 8; ++p) {
        int u = tid + p*1024;
        int row = u >> 5, cu = u & 31;
        F8 f = load8(wc, (i*HH + row)*HH + cu*8, isf32);
        unsigned short tmp[8];
#pragma unroll
        for (int j = 0; j < 8; ++j) tmp[j] = f2bf(f.v[j]);
        *(uint4*)(Ws + row*256 + ((cu ^ (row & 7)) << 3)) = *(const uint4*)tmp;
    }

    // staging roles: thread covers one 16B unit of the 256x32 ctx chunk
    const int trow = tid >> 2;        // m-row within tile (0..255)
    const int tu   = tid & 3;         // k-unit (0..3) -> coalesced 64B per row

    // ---- prologue: prefetch chunk (mc=0,kc=0) into registers ----
    uint4 gbuf = *(const uint4*)(ctx_hist + trow*HH + tu*8);

    for (int mc = 0; mc < 8; ++mc) {
        f32x16 acc[2][2];
#pragma unroll
        for (int a = 0; a < 2; ++a)
#pragma unroll
            for (int n = 0; n < 2; ++n)
#pragma unroll
                for (int r = 0; r < 16; ++r) acc[a][n][r] = 0.0f;

#pragma unroll
        for (int kc = 0; kc < 8; ++kc) {
            unsigned short* Ac = (kc & 1) ? As1 : As0;
            // write register-staged chunk to [unit][row] layout
            *(uint4*)(Ac + (tu*256 + trow)*8) = gbuf;
            __syncthreads();   // chunk visible; prev buffer's readers all past
            // prefetch next chunk (overlaps MFMA phase; drained at next barrier)
            {
                const int c = mc*8 + kc;
                if (c < 63) {
                    const int nc = c + 1;
                    const int nm0 = (nc >> 3) * 256, nk0 = (nc & 7) * 32;
                    gbuf = *(const uint4*)(ctx_hist + (nm0 + trow)*HH + nk0 + tu*8);
                }
            }
#pragma unroll
            for (int ks = 0; ks < 2; ++ks) {
                // A operand: wc fragments from resident Ws (free dim = j)
                const int uA  = kc*4 + ks*2 + lhi;          // k-unit 0..31
                const int rj0 = jq*64 + l31;
                const int rj1 = rj0 + 32;
                bf16x8 w0 = *(const bf16x8*)(Ws + rj0*256 + ((uA ^ (rj0 & 7)) << 3));
                bf16x8 w1 = *(const bf16x8*)(Ws + rj1*256 + ((uA ^ (rj1 & 7)) << 3));
                // B operand: ctx fragments from As chunk (free dim = m)
                const int uB  = ks*2 + lhi;                 // 0..3
                const int rm0 = ms*64 + l31;
                const int rm1 = rm0 + 32;
                bf16x8 b0 = *(const bf16x8*)(Ac + (uB*256 + rm0)*8);
                bf16x8 b1 = *(const bf16x8*)(Ac + (uB*256 + rm1)*8);
                acc[0][0] = __builtin_amdgcn_mfma_f32_32x32x16_bf16(w0, b0, acc[0][0], 0, 0, 0);
                acc[0][1] = __builtin_amdgcn_mfma_f32_32x32x16_bf16(w0, b1, acc[0][1], 0, 0, 0);
                acc[1][0] = __builtin_amdgcn_mfma_f32_32x32x16_bf16(w1, b0, acc[1][0], 0, 0, 0);
                acc[1][1] = __builtin_amdgcn_mfma_f32_32x32x16_bf16(w1, b1, acc[1][1], 0, 0, 0);
            }
        }

        // ---- register-lean epilogue (once per mc) ----
        // acc[a][n][r] holds TM^T[j, m]: j = jq*64+a*32+(r&3)+8*(r>>2)+4*lhi,
        // m = mc*256+ms*64+n*32+l31.  out[m] += (acc+bc[j]) * ipT[j][m].
        // Live set: sv[2], b4[4], one row pointer, two scalar ip loads.
        float sv0 = 0.0f, sv1 = 0.0f;
#pragma unroll
        for (int a = 0; a < 2; ++a) {
#pragma unroll
            for (int g = 0; g < 4; ++g) {
                const int jb = jq*64 + a*32 + g*8 + lhi*4;   // j row of acc reg g*4+q (q=0..3)
                float b4[4];
                if (isf32) {
                    float4 t = *(const float4*)((const float*)bc + i*HH + jb);
                    b4[0]=t.x; b4[1]=t.y; b4[2]=t.z; b4[3]=t.w;
                } else {
                    ushort4 t = *(const ushort4*)((const unsigned short*)bc + i*HH + jb);
                    b4[0]=bf2f(t.x); b4[1]=bf2f(t.y); b4[2]=bf2f(t.z); b4[3]=bf2f(t.w);
                }
                const unsigned short* prow =
                    ipT + (size_t)jb*MM + (mc*256 + ms*64 + l31);
#pragma unroll
                for (int q = 0; q < 4; ++q) {
                    const float ip0 = bf2f(prow[(size_t)q*MM]);        // n=0 col
                    const float ip1 = bf2f(prow[(size_t)q*MM + 32]);   // n=1 col
                    sv0 = fmaf(acc[a][0][g*4+q] + b4[q], ip0, sv0);
                    sv1 = fmaf(acc[a][1][g*4+q] + b4[q], ip1, sv1);
                }
            }
        }
        sv0 += __shfl_xor(sv0, 32);   // combine lhi halves (same m column)
        sv1 += __shfl_xor(sv1, 32);
        // Ps overlays As0; last chunk (kc=7) read As1, so As0 is dead here.
        if (lhi == 0) {
            Ps[jq*256 + ms*64 +      l31] = sv0;
            Ps[jq*256 + ms*64 + 32 + l31] = sv1;
        }
        __syncthreads();
        if (tid < 256) {
            const float r = Ps[tid] + Ps[256+tid] + Ps[512+tid] + Ps[768+tid];
            outT[(size_t)i*MM + mc*256 + tid] = r;   // coalesced 1KB row chunk
        }
        __syncthreads();   // Ps reads done before next mc's kc=0 writes As0
    }
}

// ---------------------------------------------------------------------------
// K4: transpose outT[256 i][2048 m] f32 -> out[m][i] (+ hidden dup region).
// ---------------------------------------------------------------------------
__global__ __launch_bounds__(256) void k4_tr(
    const float* __restrict__ outT,
    const int* __restrict__ flagp,
    void* __restrict__ out)
{
    const int isf32 = *flagp;
    __shared__ float tile[64][65];
    const int t  = threadIdx.x;
    const int bm = blockIdx.x * 64;   // m base
    const int bi = blockIdx.y * 64;   // i base
#pragma unroll
    for (int p = 0; p < 16; ++p) {
        const int u = t + p*256;
        const int r = u >> 6, c = u & 63;          // r = i offset, c = m offset
        tile[r][c] = outT[(size_t)(bi + r)*MM + bm + c];
    }
    __syncthreads();
#pragma unroll
    for (int p = 0; p < 16; ++p) {
        const int u = t + p*256;
        const int r = u >> 6, c = u & 63;          // r = m offset, c = i offset
        const float v = tile[c][r];
        const int m = bm + r;
        if (isf32) {
            float* o = (float*)out;
            o[(size_t)m*HH + bi + c] = v;
            if (m >= MM - BB) o[(size_t)MM*HH + (m - (MM-BB))*HH + bi + c] = v;
        } else {
            unsigned short* o = (unsigned short*)out;
            const unsigned short vb = f2bf(v);
            o[(size_t)m*HH + bi + c] = vb;
            if (m >= MM - BB) o[(size_t)MM*HH + (m - (MM-BB))*HH + bi + c] = vb;
        }
    }
}

// ---------------------------------------------------------------------------
extern "C" void kernel_launch(void* const* d_in, const int* in_sizes, int n_in,
                              void* d_out, int out_size, void* d_ws, size_t ws_size,
                              hipStream_t stream) {
    const void* x     = d_in[0];
    const void* w_i2h = d_in[1];
    const void* b_i2h = d_in[2];
    // d_in[3]=w_h2h, d_in[4]=b_h2h: dead code (reference overwrites hidden=transformed)
    const void* w_i2c = d_in[5];
    const void* b_i2c = d_in[6];
    const void* w_c2c = d_in[7];
    const void* b_c2c = d_in[8];
    const void* w_c2t = d_in[9];
    const void* b_c2t = d_in[10];
    const int* ns     = (const int*)d_in[11];

    // ws layout: ipT bf16 [256,2048] | ctx_hist bf16 [2048,256] |
    //            cin f32 [2048,256] (reused as outT f32 [256,2048]) | flag int
    unsigned short* ipT = (unsigned short*)d_ws;
    unsigned short* ch  = (unsigned short*)((char*)d_ws + (size_t)MM*HH*2);
    float* cin          = (float*)((char*)d_ws + (size_t)MM*HH*4);
    float* outT         = cin;   // k2 consumes cin before k3 writes outT
    int* flag           = (int*)((char*)d_ws + (size_t)MM*HH*8);

    // allow 160 KiB dynamic LDS for k3 (host-side attribute; capture-safe)
    (void)hipFuncSetAttribute((const void*)k3_main,
                              hipFuncAttributeMaxDynamicSharedMemorySize, 163840);

    k0_sniff<<<1, 256, 0, stream>>>((const unsigned short*)x, flag);
    k1_proj<<<64, 256, 0, stream>>>(x, w_i2h, b_i2h, w_i2c, b_i2c, flag, ipT, cin);
    k2_ctx<<<BB, 256, 0, stream>>>(w_c2c, b_c2c, cin, ns, flag, ch, d_out);
    k3_main<<<256, 1024, 163840, stream>>>(ch, w_c2t, b_c2t, ipT, flag, outT);
    k4_tr<<<dim3(32, 4), 256, 0, stream>>>(outT, flag, d_out);
}

// Round 6
// 362.984 us; speedup vs baseline: 1.2716x; 1.2716x over previous
//
#include <hip/hip_runtime.h>

// Problem constants (T=64, B=32, I=128, H=256, alpha=0.2)
#define TT 64
#define BB 32
#define II 128
#define HH 256
#define MM (TT*BB)   // 2048

typedef __bf16  bf16x8  __attribute__((ext_vector_type(8)));
typedef float   f32x16  __attribute__((ext_vector_type(16)));
typedef _Float16 half2v __attribute__((ext_vector_type(2)));
typedef unsigned int u32;

__device__ __forceinline__ float bf2f(unsigned short u) {
    union { unsigned int i; float f; } v; v.i = ((unsigned int)u) << 16; return v.f;
}
__device__ __forceinline__ unsigned short f2bf(float f) {
    union { float f; unsigned int i; } v; v.f = f;
    unsigned int r = v.i + 0x7fffu + ((v.i >> 16) & 1u);
    return (unsigned short)(r >> 16);
}

// async 16B HBM->LDS copy, no destination VGPR. LDS base must be wave-uniform;
// hardware writes base + lane*16.
__device__ __forceinline__ void gload16(const unsigned short* g, unsigned short* l) {
    __builtin_amdgcn_global_load_lds(
        (const __attribute__((address_space(1))) u32*)g,
        (__attribute__((address_space(3))) u32*)l,
        16, 0, 0);
}

// Dual-dtype loaders: external tensors may be fp32 or bf16; runtime flag decides.
struct F8 { float v[8]; };
__device__ __forceinline__ F8 load8(const void* base, int idx, int isf32) {
    F8 r;
    if (isf32) {
        const float4* p = (const float4*)((const float*)base + idx);
        float4 a = p[0], b = p[1];
        r.v[0]=a.x; r.v[1]=a.y; r.v[2]=a.z; r.v[3]=a.w;
        r.v[4]=b.x; r.v[5]=b.y; r.v[6]=b.z; r.v[7]=b.w;
    } else {
        uint4 u = *(const uint4*)((const unsigned short*)base + idx);
        const unsigned short* p = (const unsigned short*)&u;
#pragma unroll
        for (int j = 0; j < 8; ++j) r.v[j] = bf2f(p[j]);
    }
    return r;
}
__device__ __forceinline__ float load1(const void* base, int idx, int isf32) {
    return isf32 ? ((const float*)base)[idx]
                 : bf2f(((const unsigned short*)base)[idx]);
}

__device__ __forceinline__ float fdot2f(half2v a, half2v b, float c) {
#if __has_builtin(__builtin_amdgcn_fdot2)
    return __builtin_amdgcn_fdot2(a, b, c, false);
#else
    return c + (float)a.x*(float)b.x + (float)a.y*(float)b.y;
#endif
}

// ---------------------------------------------------------------------------
// K0: dtype sniffer (fp32 read as ushorts -> ~25% have exponent >= 0xC0).
// ---------------------------------------------------------------------------
__global__ __launch_bounds__(256) void k0_sniff(
    const unsigned short* __restrict__ x, int* __restrict__ flag)
{
    __shared__ int cnt;
    if (threadIdx.x == 0) cnt = 0;
    __syncthreads();
    int c = 0;
    for (int i = threadIdx.x; i < 8192; i += 256) {
        unsigned int e = (x[i] >> 7) & 0xFFu;
        if (e >= 0xC0u) ++c;
    }
    atomicAdd(&cnt, c);
    __syncthreads();
    if (threadIdx.x == 0) flag[0] = (cnt > 16) ? 1 : 0;
}

// ---------------------------------------------------------------------------
// K1 (unchanged): emits ipT[j][m] via LDS transpose.
// ---------------------------------------------------------------------------
__global__ __launch_bounds__(256) void k1_proj(
    const void* __restrict__ x,
    const void* __restrict__ w_i2h,
    const void* __restrict__ b_i2h,
    const void* __restrict__ w_i2c,
    const void* __restrict__ b_i2c,
    const int* __restrict__ flagp,
    unsigned short* __restrict__ ipT,
    float* __restrict__ cin)
{
    const int isf32 = *flagp;
    const int tid = threadIdx.x;
    const int h = tid;
    const int mbase = blockIdx.x * 32;
    __shared__ __align__(16) _Float16 xs[32][II];          // 8 KB
    __shared__ __align__(16) unsigned short ips[32][HH];   // 16 KB

    half2v w1[II/2], w2[II/2];
#pragma unroll
    for (int c8 = 0; c8 < II/8; ++c8) {
        F8 f1 = load8(w_i2h, h*II + c8*8, isf32);
        F8 f2 = load8(w_i2c, h*II + c8*8, isf32);
#pragma unroll
        for (int j = 0; j < 4; ++j) {
            half2v a; a.x = (_Float16)f1.v[2*j]; a.y = (_Float16)f1.v[2*j+1];
            half2v b; b.x = (_Float16)f2.v[2*j]; b.y = (_Float16)f2.v[2*j+1];
            w1[c8*4 + j] = a;
            w2[c8*4 + j] = b;
        }
    }
    const float bb1 = load1(b_i2h, h, isf32);
    const float bb2 = load1(b_i2c, h, isf32);

    for (int u = tid; u < 32*II; u += 256)
        xs[u >> 7][u & (II-1)] = (_Float16)load1(x, (mbase + (u >> 7))*II + (u & (II-1)), isf32);
    __syncthreads();

    for (int mm = 0; mm < 32; ++mm) {
        const half2v* xv = (const half2v*)xs[mm];
        float a0=0,a1=0,a2=0,a3=0, c0=0,c1=0,c2=0,c3=0;
#pragma unroll
        for (int r = 0; r < II/2; r += 4) {
            half2v x0 = xv[r], x1 = xv[r+1], x2 = xv[r+2], x3 = xv[r+3];
            a0 = fdot2f(w1[r],   x0, a0);
            a1 = fdot2f(w1[r+1], x1, a1);
            a2 = fdot2f(w1[r+2], x2, a2);
            a3 = fdot2f(w1[r+3], x3, a3);
            c0 = fdot2f(w2[r],   x0, c0);
            c1 = fdot2f(w2[r+1], x1, c1);
            c2 = fdot2f(w2[r+2], x2, c2);
            c3 = fdot2f(w2[r+3], x3, c3);
        }
        ips[mm][h] = f2bf(((a0+a1)+(a2+a3)) + bb1);
        cin[(mbase+mm)*HH + h] = ((c0+c1)+(c2+c3)) + bb2;
    }
    __syncthreads();
    unsigned short tmp[32];
#pragma unroll
    for (int mm = 0; mm < 32; ++mm) tmp[mm] = ips[mm][tid];
    uint4* dst = (uint4*)(ipT + (size_t)tid*MM + mbase);
    const uint4* s4 = (const uint4*)tmp;
    dst[0] = s4[0]; dst[1] = s4[1]; dst[2] = s4[2]; dst[3] = s4[3];
}

// ---------------------------------------------------------------------------
// K2 (unchanged): per-sample context chains, double-buffered LDS.
// ---------------------------------------------------------------------------
__global__ __launch_bounds__(256) void k2_ctx(
    const void* __restrict__ w_c2c,
    const void* __restrict__ b_c2c,
    const float* __restrict__ cin,
    const int* __restrict__ ns_ptr,
    const int* __restrict__ flagp,
    unsigned short* __restrict__ ctx_hist,
    void* __restrict__ out_base)
{
    const int isf32 = *flagp;
    const int b = blockIdx.x;
    const int h = threadIdx.x;
    const int ns = max(1, *ns_ptr);

    __shared__ __align__(16) _Float16 cs[2][HH];

    half2v w[HH/2];
#pragma unroll
    for (int c8 = 0; c8 < HH/8; ++c8) {
        F8 f = load8(w_c2c, h*HH + c8*8, isf32);
#pragma unroll
        for (int j = 0; j < 4; ++j) {
            half2v hv;
            hv.x = (_Float16)f.v[2*j];
            hv.y = (_Float16)f.v[2*j+1];
            w[c8*4 + j] = hv;
        }
    }
    const float bcc = load1(b_c2c, h, isf32);
    float ctxv = 0.0f;
    cs[0][h] = (_Float16)0.0f;
    __syncthreads();
    int cur = 0;

    for (int t = 0; t < TT; ++t) {
        const float cinv = cin[(t*BB + b)*HH + h];
        for (int s = 0; s < ns; ++s) {
            if (s == ns-1) ctx_hist[(t*BB + b)*HH + h] = f2bf(ctxv);
            float p0=0,p1=0,p2=0,p3=0;
            const float4* cp4 = (const float4*)cs[cur];
#pragma unroll
            for (int r4 = 0; r4 < HH/8; ++r4) {
                float4 blob = cp4[r4];
                const half2v* c2 = (const half2v*)&blob;
                p0 = fdot2f(w[r4*4+0], c2[0], p0);
                p1 = fdot2f(w[r4*4+1], c2[1], p1);
                p2 = fdot2f(w[r4*4+2], c2[2], p2);
                p3 = fdot2f(w[r4*4+3], c2[3], p3);
            }
            float cnew = fmaxf(((p0+p1)+(p2+p3)) + bcc + cinv, 0.0f);
            ctxv = 0.8f*ctxv + 0.2f*cnew;
            cs[cur^1][h] = (_Float16)ctxv;
            cur ^= 1;
            __syncthreads();
        }
    }
    const int cofs = MM*HH + BB*HH + b*HH + h;
    if (isf32) ((float*)out_base)[cofs] = ctxv;
    else       ((unsigned short*)out_base)[cofs] = f2bf(ctxv);
}

// ---------------------------------------------------------------------------
// K3 v8b: spill-free 16-wave GEMM (v8 with explicitly wave-uniform DMA base).
//  * ctx staging via global_load_lds (no dest VGPR, no live-across-barrier
//    gbuf -> the v6/v7 scratch spill class is eliminated). As [unit][row]
//    layout is lane-linear; DMA base is (tid & ~63) so HW's base + lane*16
//    lands at tid*16 with a provably uniform base operand.
//  * bc folded into the MFMA accumulator INIT (C+=A*B with C0=bc[j]):
//    epilogue is a pure sum_j acc*ipT[j][m] with ~10 live VGPRs.
//  * issue-after-barrier prefetch: chunk kc+1's DMA issues right after the
//    kc barrier and drains at the kc+1 barrier -> full MFMA phase of overlap.
// Budget: acc 64 AGPR + ~45 VGPR < 128/wave cap @ 4 waves/SIMD.
// ---------------------------------------------------------------------------
__global__ __launch_bounds__(1024, 4) void k3_main(
    const unsigned short* __restrict__ ctx_hist,  // [2048 m,256 k] bf16 (internal)
    const void* __restrict__ wc,                  // [65536,256] external
    const void* __restrict__ bc,                  // [65536]     external
    const unsigned short* __restrict__ ipT,       // [256 j][2048 m] bf16 (internal)
    const int* __restrict__ flagp,
    float* __restrict__ outT)                     // [256 i][2048 m] f32 (internal)
{
    extern __shared__ __align__(16) unsigned char lds[];
    unsigned short* Ws  = (unsigned short*)lds;              // 131072 B
    unsigned short* As0 = (unsigned short*)(lds + 131072);   // 16384 B
    unsigned short* As1 = (unsigned short*)(lds + 147456);   // 16384 B
    float*          Ps  = (float*)(lds + 131072);            // 4 KB overlay on As0

    const int isf32 = *flagp;
    const int tid  = threadIdx.x;
    const int lane = tid & 63;
    const int wave = tid >> 6;        // 0..15
    const int i    = blockIdx.x;      // 0..255
    const int jq   = wave & 3;        // j quarter (64 rows)
    const int ms   = wave >> 2;       // m quarter (64 cols)
    const int l31  = lane & 31;
    const int lhi  = lane >> 5;

    // ---- stage Ws once: 256 j-rows x 256 k -> bf16, swizzled; 8 units/thread
#pragma unroll
    for (int p = 0; p < 8; ++p) {
        int u = tid + p*1024;
        int row = u >> 5, cu = u & 31;
        F8 f = load8(wc, (i*HH + row)*HH + cu*8, isf32);
        unsigned short tmp[8];
#pragma unroll
        for (int j = 0; j < 8; ++j) tmp[j] = f2bf(f.v[j]);
        *(uint4*)(Ws + row*256 + ((cu ^ (row & 7)) << 3)) = *(const uint4*)tmp;
    }

    // DMA staging roles: wave-uniform LDS base (HW adds lane*16), per-lane src.
    const int trow = tid & 255;       // m-row within 256-row tile
    const int tu   = tid >> 8;        // k-unit (0..3)
    const int wbofs = (tid & ~63) * 8;            // uniform per wave (elems)
    unsigned short* wAs0 = As0 + wbofs;
    unsigned short* wAs1 = As1 + wbofs;

    // fragment address bases (per-thread constants)
    const int rj0 = jq*64 + l31;              // Ws rows (xor mask same for +32)
    const int xm  = rj0 & 7;
    const unsigned short* wp0 = Ws + rj0*256;
    const unsigned short* wp1 = Ws + (rj0+32)*256;
    const int abase = ((ms*64 + l31) + lhi*256)*8;   // As frag offset (elems)

    // ---- prologue: issue DMA for chunk (mc=0,kc=0) into As0 ----
    gload16(ctx_hist + trow*HH + tu*8, wAs0);

#pragma unroll 1
    for (int mc = 0; mc < 8; ++mc) {
        const unsigned short* gsrc = ctx_hist + (mc*256 + trow)*HH + tu*8;

        // ---- acc init = bc[j] broadcast across m (folds bias into GEMM) ----
        f32x16 acc[2][2];
#pragma unroll
        for (int a = 0; a < 2; ++a)
#pragma unroll
            for (int g = 0; g < 4; ++g) {
                const int jb = i*HH + jq*64 + a*32 + g*8 + lhi*4;
                float b0, b1, b2, b3;
                if (isf32) {
                    float4 t = *(const float4*)((const float*)bc + jb);
                    b0 = t.x; b1 = t.y; b2 = t.z; b3 = t.w;
                } else {
                    ushort4 t = *(const ushort4*)((const unsigned short*)bc + jb);
                    b0 = bf2f(t.x); b1 = bf2f(t.y); b2 = bf2f(t.z); b3 = bf2f(t.w);
                }
                acc[a][0][g*4+0] = b0; acc[a][1][g*4+0] = b0;
                acc[a][0][g*4+1] = b1; acc[a][1][g*4+1] = b1;
                acc[a][0][g*4+2] = b2; acc[a][1][g*4+2] = b2;
                acc[a][0][g*4+3] = b3; acc[a][1][g*4+3] = b3;
            }

#pragma unroll
        for (int kc = 0; kc < 8; ++kc) {
            __syncthreads();   // drains DMA for this chunk; syncs prev readers
            // issue DMA for chunk kc+1 into the other buffer (overlaps MFMA)
            if (kc < 7)
                gload16(gsrc + (kc+1)*32, (kc & 1) ? wAs0 : wAs1);
            const unsigned short* Ac = (kc & 1) ? As1 : As0;
#pragma unroll
            for (int ks = 0; ks < 2; ++ks) {
                const int uA = kc*4 + ks*2 + lhi;           // k-unit 0..31
                bf16x8 w0 = *(const bf16x8*)(wp0 + ((uA ^ xm) << 3));
                bf16x8 w1 = *(const bf16x8*)(wp1 + ((uA ^ xm) << 3));
                bf16x8 b0 = *(const bf16x8*)(Ac + abase + ks*4096);
                bf16x8 b1 = *(const bf16x8*)(Ac + abase + ks*4096 + 32*8);
                acc[0][0] = __builtin_amdgcn_mfma_f32_32x32x16_bf16(w0, b0, acc[0][0], 0, 0, 0);
                acc[0][1] = __builtin_amdgcn_mfma_f32_32x32x16_bf16(w0, b1, acc[0][1], 0, 0, 0);
                acc[1][0] = __builtin_amdgcn_mfma_f32_32x32x16_bf16(w1, b0, acc[1][0], 0, 0, 0);
                acc[1][1] = __builtin_amdgcn_mfma_f32_32x32x16_bf16(w1, b1, acc[1][1], 0, 0, 0);
            }
        }

        // ---- lean epilogue: out[m] = sum_j acc[j,m] * ipT[j][m] ----
        // acc row j = jq*64 + a*32 + (r&3) + 8*(r>>2) + 4*lhi; col m = mcol(+32n)
        float sv0 = 0.0f, sv1 = 0.0f;
        const int mcol = mc*256 + ms*64 + l31;
#pragma unroll
        for (int a = 0; a < 2; ++a)
#pragma unroll
            for (int g = 0; g < 4; ++g) {
                const unsigned short* prow =
                    ipT + (jq*64 + a*32 + g*8 + lhi*4)*MM + mcol;
#pragma unroll
                for (int q = 0; q < 4; ++q) {
                    sv0 = fmaf(acc[a][0][g*4+q], bf2f(prow[q*MM]),      sv0);
                    sv1 = fmaf(acc[a][1][g*4+q], bf2f(prow[q*MM + 32]), sv1);
                }
            }
        sv0 += __shfl_xor(sv0, 32);   // combine lhi halves (same m column)
        sv1 += __shfl_xor(sv1, 32);
        // Ps overlays As0: last As0 read was kc=6 (all waves past kc=7 barrier),
        // and no DMA into As0 is outstanding (kc=7 issued none).
        if (lhi == 0) {
            Ps[jq*256 + ms*64 +      l31] = sv0;
            Ps[jq*256 + ms*64 + 32 + l31] = sv1;
        }
        __syncthreads();
        if (tid < 256) {
            const float r = Ps[tid] + Ps[256+tid] + Ps[512+tid] + Ps[768+tid];
            outT[(size_t)i*MM + mc*256 + tid] = r;   // coalesced 1KB row chunk
        }
        __syncthreads();   // Ps reads done before As0 is overwritten
        // issue DMA for next mc's chunk 0 into As0 (drained at next kc=0 barrier)
        if (mc < 7)
            gload16(ctx_hist + ((mc+1)*256 + trow)*HH + tu*8, wAs0);
    }
}

// ---------------------------------------------------------------------------
// K4: transpose outT[256 i][2048 m] f32 -> out[m][i] (+ hidden dup region).
// ---------------------------------------------------------------------------
__global__ __launch_bounds__(256) void k4_tr(
    const float* __restrict__ outT,
    const int* __restrict__ flagp,
    void* __restrict__ out)
{
    const int isf32 = *flagp;
    __shared__ float tile[64][65];
    const int t  = threadIdx.x;
    const int bm = blockIdx.x * 64;   // m base
    const int bi = blockIdx.y * 64;   // i base
#pragma unroll
    for (int p = 0; p < 16; ++p) {
        const int u = t + p*256;
        const int r = u >> 6, c = u & 63;          // r = i offset, c = m offset
        tile[r][c] = outT[(size_t)(bi + r)*MM + bm + c];
    }
    __syncthreads();
#pragma unroll
    for (int p = 0; p < 16; ++p) {
        const int u = t + p*256;
        const int r = u >> 6, c = u & 63;          // r = m offset, c = i offset
        const float v = tile[c][r];
        const int m = bm + r;
        if (isf32) {
            float* o = (float*)out;
            o[(size_t)m*HH + bi + c] = v;
            if (m >= MM - BB) o[(size_t)MM*HH + (m - (MM-BB))*HH + bi + c] = v;
        } else {
            unsigned short* o = (unsigned short*)out;
            const unsigned short vb = f2bf(v);
            o[(size_t)m*HH + bi + c] = vb;
            if (m >= MM - BB) o[(size_t)MM*HH + (m - (MM-BB))*HH + bi + c] = vb;
        }
    }
}

// ---------------------------------------------------------------------------
extern "C" void kernel_launch(void* const* d_in, const int* in_sizes, int n_in,
                              void* d_out, int out_size, void* d_ws, size_t ws_size,
                              hipStream_t stream) {
    const void* x     = d_in[0];
    const void* w_i2h = d_in[1];
    const void* b_i2h = d_in[2];
    // d_in[3]=w_h2h, d_in[4]=b_h2h: dead code (reference overwrites hidden=transformed)
    const void* w_i2c = d_in[5];
    const void* b_i2c = d_in[6];
    const void* w_c2c = d_in[7];
    const void* b_c2c = d_in[8];
    const void* w_c2t = d_in[9];
    const void* b_c2t = d_in[10];
    const int* ns     = (const int*)d_in[11];

    // ws layout: ipT bf16 [256,2048] | ctx_hist bf16 [2048,256] |
    //            cin f32 [2048,256] (reused as outT f32 [256,2048]) | flag int
    unsigned short* ipT = (unsigned short*)d_ws;
    unsigned short* ch  = (unsigned short*)((char*)d_ws + (size_t)MM*HH*2);
    float* cin          = (float*)((char*)d_ws + (size_t)MM*HH*4);
    float* outT         = cin;   // k2 consumes cin before k3 writes outT
    int* flag           = (int*)((char*)d_ws + (size_t)MM*HH*8);

    // allow 160 KiB dynamic LDS for k3 (host-side attribute; capture-safe)
    (void)hipFuncSetAttribute((const void*)k3_main,
                              hipFuncAttributeMaxDynamicSharedMemorySize, 163840);

    k0_sniff<<<1, 256, 0, stream>>>((const unsigned short*)x, flag);
    k1_proj<<<64, 256, 0, stream>>>(x, w_i2h, b_i2h, w_i2c, b_i2c, flag, ipT, cin);
    k2_ctx<<<BB, 256, 0, stream>>>(w_c2c, b_c2c, cin, ns, flag, ch, d_out);
    k3_main<<<256, 1024, 163840, stream>>>(ch, w_c2t, b_c2t, ipT, flag, outT);
    k4_tr<<<dim3(32, 4), 256, 0, stream>>>(outT, flag, d_out);
}